// Round 3
// baseline (161.045 us; speedup 1.0000x reference)
//
#include <hip/hip_runtime.h>

// VQ-VAE forward + EMA update, MI355X.
// Sizes fixed by the reference: B=64, C=D=8, H=W=64, K=512.
constexpr int Kc   = 512;
constexpr int Dc   = 8;
constexpr int HWc  = 4096;            // 64*64
constexpr int CHWc = Dc * HWc;        // 32768
constexpr int Mc   = 64 * HWc;        // 262144 vectors
constexpr int TOTALc = Mc * Dc;       // 2097152 elements of z / z_q

// 8 replica accumulators (one per XCD via blockIdx&7) to cut atomic contention.
constexpr int REP      = 8;
constexpr int RSTRIDE  = 4616;        // 512 counts + 4096 sums + 1 loss + 7 pad
constexpr int ACC_FLOATS = REP * RSTRIDE;   // 36928 floats (~148 KB)
// d_ws float layout:
//   [0 .. ACC_FLOATS)            replica accumulators (counts | sums | loss | pad) x8
//   [ACC_FLOATS .. +512)         e_sq[k]

__global__ __launch_bounds__(256) void vq_prep(const float* __restrict__ cb,
                                               float* __restrict__ ws) {
    const int tid = blockIdx.x * 256 + threadIdx.x;
    float4* w4 = (float4*)ws;
    for (int i = tid; i < ACC_FLOATS / 4; i += gridDim.x * 256)
        w4[i] = float4{0.f, 0.f, 0.f, 0.f};
    if (blockIdx.x == 0) {
        for (int k = threadIdx.x; k < Kc; k += 256) {
            float s = 0.f;
#pragma unroll
            for (int c = 0; c < Dc; ++c) {
                const float e = cb[k * Dc + c];
                s = fmaf(e, e, s);
            }
            ws[ACC_FLOATS + k] = s;
        }
    }
}

// 1024 blocks x 512 threads; block owns 256 consecutive vectors.
// k-group g = t>>7 (2 waves) scans codes [g*128, g*128+128) for all 256
// vectors; each thread scores V=2 vectors (vl and vl+128).
// KEY CHANGE vs the 47us baseline: the codebook + esq stream is read through
// the VECTOR path (L1 broadcast loads), not the scalar K$ path. Rationale:
// r0 pulled 36 B/code/wave through K$ = ~24 B/cyc/CU sustained — a scalar-
// cache throughput ceiling consistent with VALUBusy pinned at 59%; SMEM also
// forces lgkmcnt(0) full drains (out-of-order returns), while vector loads
// get fine-grained vmcnt(N) pipelining. Pointers are laundered through an
// empty asm so the compiler cannot prove uniformity and re-scalarize.
// Bonus: e/ev now live in VGPRs, so the chain starts fma(zz0,e0,ev) — the
// per-pair v_mov is gone. Math order is BIT-IDENTICAL to r0.
__global__ __launch_bounds__(512, 8) void vq_main(const float* __restrict__ z,
                                                  const float* __restrict__ cb,
                                                  const float* __restrict__ esq,
                                                  float* __restrict__ ws,
                                                  float* __restrict__ zq) {
    __shared__ float s_mn[4][256];
    __shared__ int   s_im[4][256];
    __shared__ float s_counts[Kc];
    __shared__ float s_sums[Kc * Dc];
    __shared__ float s_loss;

    const int t = threadIdx.x;
    for (int i = t; i < Kc; i += 512) s_counts[i] = 0.f;
    for (int i = t; i < Kc * Dc; i += 512) s_sums[i] = 0.f;
    if (t == 0) s_loss = 0.f;

    const int vl = t & 127;
    const int g  = __builtin_amdgcn_readfirstlane(t >> 7);   // 0..3
    const int k0 = g << 7;

    const int base = blockIdx.x * 256;        // 256-aligned -> one batch idx
    const int n0 = (base + vl) & (HWc - 1);
    const int b  = base >> 12;
    const float* zb = z + b * CHWc + n0;

    float zz0[Dc], zz1[Dc];
#pragma unroll
    for (int c = 0; c < Dc; ++c) {
        zz0[c] = -2.0f * zb[c * HWc];         // coalesced across lanes
        zz1[c] = -2.0f * zb[c * HWc + 128];
    }

    // Launder cb/esq pointers into VGPRs: forces vector-path broadcast loads
    // (one L1 access per wave, 16KB+2KB table is L1-resident).
    unsigned long long cbp = (unsigned long long)cb;
    unsigned long long eqp = (unsigned long long)esq;
    asm("" : "+v"(cbp));
    asm("" : "+v"(eqp));
    const float4* cb4v = (const float4*)cbp;
    const float*  esqv = (const float*)eqp;

    // argmin over this k-group: score = e_sq[k] - 2*dot(z,e_k) (monotone-eq).
    float mn0 = 3.4e38f, mn1 = 3.4e38f;
    int   i0 = k0, i1 = k0;
#pragma unroll 2
    for (int kk = 0; kk < 128; ++kk) {
        const int k = k0 + kk;
        const float4 e0 = cb4v[k * 2];        // global_load_dwordx4 broadcast
        const float4 e1 = cb4v[k * 2 + 1];
        const float  ev = esqv[k];            // global_load_dword broadcast
        // identical fma order to the 47us baseline: a = ev; a+=zz[c]*e[c], c=0..7
        float a0 = fmaf(zz0[0], e0.x, ev);
        float a1 = fmaf(zz1[0], e0.x, ev);
        a0 = fmaf(zz0[1], e0.y, a0);  a1 = fmaf(zz1[1], e0.y, a1);
        a0 = fmaf(zz0[2], e0.z, a0);  a1 = fmaf(zz1[2], e0.z, a1);
        a0 = fmaf(zz0[3], e0.w, a0);  a1 = fmaf(zz1[3], e0.w, a1);
        a0 = fmaf(zz0[4], e1.x, a0);  a1 = fmaf(zz1[4], e1.x, a1);
        a0 = fmaf(zz0[5], e1.y, a0);  a1 = fmaf(zz1[5], e1.y, a1);
        a0 = fmaf(zz0[6], e1.z, a0);  a1 = fmaf(zz1[6], e1.z, a1);
        a0 = fmaf(zz0[7], e1.w, a0);  a1 = fmaf(zz1[7], e1.w, a1);
        const bool c0 = a0 < mn0;  // strict <: first index wins ties (ref)
        mn0 = c0 ? a0 : mn0;
        i0  = c0 ? k  : i0;
        const bool c1 = a1 < mn1;
        mn1 = c1 ? a1 : mn1;
        i1  = c1 ? k  : i1;
    }
    s_mn[g][vl]       = mn0;
    s_im[g][vl]       = i0;
    s_mn[g][vl + 128] = mn1;
    s_im[g][vl + 128] = i1;
    __syncthreads();

    if (t < 256) {
        const int v = t;                      // block-local vector id
        float mn = s_mn[0][v];
        int   im = s_im[0][v];
#pragma unroll
        for (int gg = 1; gg < 4; ++gg) {
            const float m2 = s_mn[gg][v];     // groups ascending in k:
            const int   j2 = s_im[gg][v];     // strict < keeps first index
            const bool  c2 = m2 < mn;
            mn = c2 ? m2 : mn;
            im = c2 ? j2 : im;
        }

        // Gather old-codebook row (16 KB table, L1-hot; 32B/lane).
        const float4* cb4 = (const float4*)cb;
        const float4 qa = cb4[im * 2], qb = cb4[im * 2 + 1];
        const float q[Dc] = {qa.x, qa.y, qa.z, qa.w, qb.x, qb.y, qb.z, qb.w};

        // z values from registers: thread t<128 holds vector t in zz0;
        // thread 128..255 holds vector t in zz1 (its vl = t-128).
        // zr = -0.5 * (-2*z) is bit-exact.
        float zr[Dc];
#pragma unroll
        for (int c = 0; c < Dc; ++c)
            zr[c] = -0.5f * ((t < 128) ? zz0[c] : zz1[c]);

        const int nv = (base & (HWc - 1)) + v;
        float* zqv = zq + b * CHWc + nv;
        float lsum = 0.f;
#pragma unroll
        for (int c = 0; c < Dc; ++c) {
            zqv[c * HWc] = q[c];              // coalesced stores
            const float d = q[c] - zr[c];
            lsum = fmaf(d, d, lsum);
        }

        // Per-block LDS histogram (ds_add_f32) — coalesces same-index hits.
        unsafeAtomicAdd(&s_counts[im], 1.0f);
#pragma unroll
        for (int c = 0; c < Dc; ++c)
            unsafeAtomicAdd(&s_sums[im * Dc + c], zr[c]);
        unsafeAtomicAdd(&s_loss, lsum);
    }
    __syncthreads();

    // Flush non-zero bins to this block's replica accumulator (all 512 thr).
    float* acc = ws + (blockIdx.x & (REP - 1)) * RSTRIDE;
    for (int i = t; i < Kc; i += 512) {
        const float val = s_counts[i];
        if (val != 0.f) unsafeAtomicAdd(&acc[i], val);
    }
    for (int i = t; i < Kc * Dc; i += 512) {
        const float val = s_sums[i];
        if (val != 0.f) unsafeAtomicAdd(&acc[512 + i], val);
    }
    if (t == 0) unsafeAtomicAdd(&acc[4608], s_loss);
}

// 9 blocks: every block redundantly recomputes the (cheap) counts/cs phase;
// block 0 writes cs + loss, blocks 1..8 each handle 512 of the 4096 K*D
// elements. Replaces the old single-block kernel whose ~72 serial L2 loads
// per thread made it latency-bound.
__global__ __launch_bounds__(512) void vq_final(const float* __restrict__ ws,
                                                const float* __restrict__ ema_cs,
                                                const float* __restrict__ ema_w,
                                                float* __restrict__ out) {
    constexpr float DEC  = 0.99f;
    constexpr float OMD  = (float)(1.0 - 0.99);      // matches jnp f32 cast
    constexpr float EPSf = 1e-5f;
    constexpr float KEPS = (float)(512 * 1e-5);      // 0.00512
    __shared__ float red[512];
    __shared__ float s_cs[512];

    const int t = threadIdx.x;
    // counts: lane-consecutive reads per replica (coalesced)
    float cnt = 0.f;
#pragma unroll
    for (int r = 0; r < REP; ++r) cnt += ws[r * RSTRIDE + t];
    const float ncs = ema_cs[t] * DEC + cnt * OMD;
    red[t] = ncs;
    __syncthreads();
    for (int s = 256; s > 0; s >>= 1) {
        if (t < s) red[t] += red[t + s];
        __syncthreads();
    }
    const float n  = red[0];
    const float cs = (ncs + EPSf) / (n + KEPS) * n;
    s_cs[t] = cs;

    float* out_loss = out + TOTALc;          // [1]
    float* out_cb   = out + TOTALc + 1;      // [K*D]
    float* out_cs   = out_cb + Kc * Dc;      // [K]
    float* out_nw   = out_cs + Kc;           // [K*D]

    __syncthreads();

    const int blk = blockIdx.x;
    if (blk == 0) {
        out_cs[t] = cs;
        if (t == 0) {
            float ls = 0.f;
#pragma unroll
            for (int r = 0; r < REP; ++r) ls += ws[r * RSTRIDE + 4608];
            out_loss[0] = ls * (1.0f / 2097152.0f);  // /2^21 exact
        }
    } else {
        const int e = (blk - 1) * 512 + t;   // one element per thread
        float sm = 0.f;
#pragma unroll
        for (int r = 0; r < REP; ++r) sm += ws[r * RSTRIDE + 512 + e];
        const float nw = ema_w[e] * DEC + sm * OMD;
        out_nw[e] = nw;
        out_cb[e] = nw / s_cs[e >> 3];
    }
}

extern "C" void kernel_launch(void* const* d_in, const int* in_sizes, int n_in,
                              void* d_out, int out_size, void* d_ws, size_t ws_size,
                              hipStream_t stream) {
    const float* z      = (const float*)d_in[0];
    const float* cb     = (const float*)d_in[1];
    const float* ema_cs = (const float*)d_in[2];
    const float* ema_w  = (const float*)d_in[3];
    float* out = (float*)d_out;
    float* ws  = (float*)d_ws;

    vq_prep<<<32, 256, 0, stream>>>(cb, ws);
    vq_main<<<Mc / 256, 512, 0, stream>>>(z, cb, ws + ACC_FLOATS, ws, out);
    vq_final<<<9, 512, 0, stream>>>(ws, ema_cs, ema_w, out);
}

// Round 4
// 109.556 us; speedup vs baseline: 1.4700x; 1.4700x over previous
//
#include <hip/hip_runtime.h>

// VQ-VAE forward + EMA update, MI355X.
// Sizes fixed by the reference: B=64, C=D=8, H=W=64, K=512.
constexpr int Kc   = 512;
constexpr int Dc   = 8;
constexpr int HWc  = 4096;            // 64*64
constexpr int CHWc = Dc * HWc;        // 32768
constexpr int Mc   = 64 * HWc;        // 262144 vectors
constexpr int TOTALc = Mc * Dc;       // 2097152 elements of z / z_q

// 8 replica accumulators (one per XCD via blockIdx&7) to cut atomic contention.
constexpr int REP      = 8;
constexpr int RSTRIDE  = 4616;        // 512 counts + 4096 sums + 1 loss + 7 pad
constexpr int ACC_FLOATS = REP * RSTRIDE;   // 36928 floats (~148 KB)
// d_ws float layout:
//   [0 .. ACC_FLOATS)            replica accumulators (counts | sums | loss | pad) x8
//   [ACC_FLOATS .. +512)         e_sq[k]

typedef float v2f __attribute__((ext_vector_type(2)));

__global__ __launch_bounds__(256) void vq_prep(const float* __restrict__ cb,
                                               float* __restrict__ ws) {
    const int tid = blockIdx.x * 256 + threadIdx.x;
    float4* w4 = (float4*)ws;
    for (int i = tid; i < ACC_FLOATS / 4; i += gridDim.x * 256)
        w4[i] = float4{0.f, 0.f, 0.f, 0.f};
    if (blockIdx.x == 0) {
        for (int k = threadIdx.x; k < Kc; k += 256) {
            float s = 0.f;
#pragma unroll
            for (int c = 0; c < Dc; ++c) {
                const float e = cb[k * Dc + c];
                s = fmaf(e, e, s);
            }
            ws[ACC_FLOATS + k] = s;
        }
    }
}

// 1024 blocks x 512 threads; block owns 256 consecutive vectors.
// 8 k-groups x 1 wave: wave g scans codes [g*64, g*64+64) — UNIQUE codes per
// wave (r0 duplicated each s_load across 2 waves; scalar traffic now halved).
// Lane l scores V=4 vectors (l, l+64, l+128, l+192) packed as two f32-pairs.
// Inner product uses v_pk_fma_f32 (2 FMAs/instr): codebook c-pair sits in an
// even-aligned SGPR pair ("s"(uint64)), broadcast to both halves via
// op_sel/op_sel_hi — 1 SGPR source per instr, no splat movs.
// Math is BIT-IDENTICAL to the 47us baseline: a = esq[k]; a += zz[c]*e[c]
// for c = 0..7 ascending; strict-< first-index-wins; groups ascending in k.
__global__ __launch_bounds__(512, 8) void vq_main(const float* __restrict__ z,
                                                  const float* __restrict__ cb,
                                                  const float* __restrict__ esq,
                                                  float* __restrict__ ws,
                                                  float* __restrict__ zq) {
    __shared__ float s_mn[8][256];         // 8 KB
    __shared__ int   s_im[8][256];         // 8 KB
    __shared__ float s_counts[Kc];         // 2 KB
    __shared__ float s_sums[Kc * Dc];      // 16 KB
    __shared__ float s_loss;

    const int t = threadIdx.x;
    for (int i = t; i < Kc; i += 512) s_counts[i] = 0.f;
    for (int i = t; i < Kc * Dc; i += 512) s_sums[i] = 0.f;
    if (t == 0) s_loss = 0.f;

    const int l = t & 63;
    // wave-uniform k-group; readfirstlane keeps codebook indices provably
    // uniform -> s_load (scalar) path for cb/esq.
    const int g  = __builtin_amdgcn_readfirstlane(t >> 6);   // 0..7
    const int k0 = g << 6;

    const int base = blockIdx.x * 256;        // 256-aligned -> one batch idx
    const int b  = base >> 12;
    const int n0 = (base & (HWc - 1)) + l;    // +64*j below never wraps 4096
    const float* zb = z + b * CHWc + n0;

    // zzA[c] = (-2*z[vec l][c], -2*z[vec l+64][c]); zzB: vecs l+128, l+192.
    v2f zzA[Dc], zzB[Dc];
#pragma unroll
    for (int c = 0; c < Dc; ++c) {
        zzA[c] = v2f{-2.0f * zb[c * HWc],       -2.0f * zb[c * HWc + 64]};
        zzB[c] = v2f{-2.0f * zb[c * HWc + 128], -2.0f * zb[c * HWc + 192]};
    }

    const unsigned long long* cbq = (const unsigned long long*)cb; // 4 qw/row

    float mn0 = 3.4e38f, mn1 = 3.4e38f, mn2 = 3.4e38f, mn3 = 3.4e38f;
    int   i0 = k0, i1 = k0, i2 = k0, i3 = k0;
#pragma unroll 2
    for (int kk = 0; kk < 64; ++kk) {
        const int k = k0 + kk;
        const unsigned long long q0 = cbq[4 * k + 0];  // (e0,e1) uniform
        const unsigned long long q1 = cbq[4 * k + 1];  // (e2,e3)
        const unsigned long long q2 = cbq[4 * k + 2];  // (e4,e5)
        const unsigned long long q3 = cbq[4 * k + 3];  // (e6,e7)
        const float ev = esq[k];                       // uniform -> s_load
        v2f aA = {ev, ev};
        v2f aB = {ev, ev};
        // Each asm: 4 pk_fma = 2 c-steps x 2 vector-pairs. op_sel_hi:[1,0,1]
        // broadcasts the LOW dword of the sgpr pair (e[2p]); op_sel:[0,1,0]
        // (with default op_sel_hi [1,1,1]) broadcasts the HIGH dword (e[2p+1]).
        // Per-acc chain order: c=2p then c=2p+1 -> ascending c, exact.
#define PKSTEP(Q, P0, P1)                                              \
        asm("v_pk_fma_f32 %0, %2, %4, %0 op_sel_hi:[1,0,1]\n\t"        \
            "v_pk_fma_f32 %1, %3, %4, %1 op_sel_hi:[1,0,1]\n\t"        \
            "v_pk_fma_f32 %0, %5, %4, %0 op_sel:[0,1,0]\n\t"           \
            "v_pk_fma_f32 %1, %6, %4, %1 op_sel:[0,1,0]"               \
            : "+v"(aA), "+v"(aB)                                       \
            : "v"(zzA[P0]), "v"(zzB[P0]), "s"(Q), "v"(zzA[P1]), "v"(zzB[P1]))
        PKSTEP(q0, 0, 1);
        PKSTEP(q1, 2, 3);
        PKSTEP(q2, 4, 5);
        PKSTEP(q3, 6, 7);
#undef PKSTEP
        const float a0 = aA.x, a1 = aA.y, a2 = aB.x, a3 = aB.y;
        bool c;
        c = a0 < mn0; mn0 = c ? a0 : mn0; i0 = c ? k : i0;
        c = a1 < mn1; mn1 = c ? a1 : mn1; i1 = c ? k : i1;
        c = a2 < mn2; mn2 = c ? a2 : mn2; i2 = c ? k : i2;
        c = a3 < mn3; mn3 = c ? a3 : mn3; i3 = c ? k : i3;
    }
    s_mn[g][l]       = mn0;  s_im[g][l]       = i0;
    s_mn[g][l +  64] = mn1;  s_im[g][l +  64] = i1;
    s_mn[g][l + 128] = mn2;  s_im[g][l + 128] = i2;
    s_mn[g][l + 192] = mn3;  s_im[g][l + 192] = i3;
    __syncthreads();

    if (t < 256) {
        const int v = t;                      // block-local vector id
        float mn = s_mn[0][v];
        int   im = s_im[0][v];
#pragma unroll
        for (int gg = 1; gg < 8; ++gg) {
            const float m2 = s_mn[gg][v];     // groups ascending in k:
            const int   j2 = s_im[gg][v];     // strict < keeps first index
            const bool  c2 = m2 < mn;
            mn = c2 ? m2 : mn;
            im = c2 ? j2 : im;
        }

        // Gather old-codebook row (16 KB table, L1-hot; 32B/lane).
        const float4* cb4 = (const float4*)cb;
        const float4 qa = cb4[im * 2], qb = cb4[im * 2 + 1];
        const float q[Dc] = {qa.x, qa.y, qa.z, qa.w, qb.x, qb.y, qb.z, qb.w};

        const int nv = (base & (HWc - 1)) + v;
        const float* zv = z + b * CHWc + nv;  // re-read z (L1/L2-hot)
        float* zqv = zq + b * CHWc + nv;
        float lsum = 0.f;
        float zr[Dc];
#pragma unroll
        for (int c = 0; c < Dc; ++c) {
            zr[c] = zv[c * HWc];
            zqv[c * HWc] = q[c];              // coalesced stores
            const float d = q[c] - zr[c];
            lsum = fmaf(d, d, lsum);
        }

        // Per-block LDS histogram (ds_add_f32) — coalesces same-index hits.
        unsafeAtomicAdd(&s_counts[im], 1.0f);
#pragma unroll
        for (int c = 0; c < Dc; ++c)
            unsafeAtomicAdd(&s_sums[im * Dc + c], zr[c]);
        unsafeAtomicAdd(&s_loss, lsum);
    }
    __syncthreads();

    // Flush non-zero bins to this block's replica accumulator (all 512 thr).
    float* acc = ws + (blockIdx.x & (REP - 1)) * RSTRIDE;
    for (int i = t; i < Kc; i += 512) {
        const float val = s_counts[i];
        if (val != 0.f) unsafeAtomicAdd(&acc[i], val);
    }
    for (int i = t; i < Kc * Dc; i += 512) {
        const float val = s_sums[i];
        if (val != 0.f) unsafeAtomicAdd(&acc[512 + i], val);
    }
    if (t == 0) unsafeAtomicAdd(&acc[4608], s_loss);
}

// 9 blocks: every block redundantly recomputes the (cheap) counts/cs phase;
// block 0 writes cs + loss, blocks 1..8 each handle 512 of the 4096 K*D
// elements.
__global__ __launch_bounds__(512) void vq_final(const float* __restrict__ ws,
                                                const float* __restrict__ ema_cs,
                                                const float* __restrict__ ema_w,
                                                float* __restrict__ out) {
    constexpr float DEC  = 0.99f;
    constexpr float OMD  = (float)(1.0 - 0.99);      // matches jnp f32 cast
    constexpr float EPSf = 1e-5f;
    constexpr float KEPS = (float)(512 * 1e-5);      // 0.00512
    __shared__ float red[512];
    __shared__ float s_cs[512];

    const int t = threadIdx.x;
    // counts: lane-consecutive reads per replica (coalesced)
    float cnt = 0.f;
#pragma unroll
    for (int r = 0; r < REP; ++r) cnt += ws[r * RSTRIDE + t];
    const float ncs = ema_cs[t] * DEC + cnt * OMD;
    red[t] = ncs;
    __syncthreads();
    for (int s = 256; s > 0; s >>= 1) {
        if (t < s) red[t] += red[t + s];
        __syncthreads();
    }
    const float n  = red[0];
    const float cs = (ncs + EPSf) / (n + KEPS) * n;
    s_cs[t] = cs;

    float* out_loss = out + TOTALc;          // [1]
    float* out_cb   = out + TOTALc + 1;      // [K*D]
    float* out_cs   = out_cb + Kc * Dc;      // [K]
    float* out_nw   = out_cs + Kc;           // [K*D]

    __syncthreads();

    const int blk = blockIdx.x;
    if (blk == 0) {
        out_cs[t] = cs;
        if (t == 0) {
            float ls = 0.f;
#pragma unroll
            for (int r = 0; r < REP; ++r) ls += ws[r * RSTRIDE + 4608];
            out_loss[0] = ls * (1.0f / 2097152.0f);  // /2^21 exact
        }
    } else {
        const int e = (blk - 1) * 512 + t;   // one element per thread
        float sm = 0.f;
#pragma unroll
        for (int r = 0; r < REP; ++r) sm += ws[r * RSTRIDE + 512 + e];
        const float nw = ema_w[e] * DEC + sm * OMD;
        out_nw[e] = nw;
        out_cb[e] = nw / s_cs[e >> 3];
    }
}

extern "C" void kernel_launch(void* const* d_in, const int* in_sizes, int n_in,
                              void* d_out, int out_size, void* d_ws, size_t ws_size,
                              hipStream_t stream) {
    const float* z      = (const float*)d_in[0];
    const float* cb     = (const float*)d_in[1];
    const float* ema_cs = (const float*)d_in[2];
    const float* ema_w  = (const float*)d_in[3];
    float* out = (float*)d_out;
    float* ws  = (float*)d_ws;

    vq_prep<<<32, 256, 0, stream>>>(cb, ws);
    vq_main<<<Mc / 256, 512, 0, stream>>>(z, cb, ws + ACC_FLOATS, ws, out);
    vq_final<<<9, 512, 0, stream>>>(ws, ema_cs, ema_w, out);
}